// Round 3
// baseline (339.413 us; speedup 1.0000x reference)
//
#include <hip/hip_runtime.h>

// LightshiftaddLayer — R8:
//  gemm_bt: 256->512 threads, same 128x128 tile + 32KB dbuf LDS + T2 swizzle
//    + gload_lds(B). 8 waves (2x4), 64x32 per wave -> per-wave regs ~halve ->
//    launch_bounds(512,6) = 3 blocks x 8 waves = 24 waves/CU (was 12).
//    Occupancy has tracked time linearly across R5/R6/R7 (28%/108, 20%/116,
//    37%/96); this doubles resident waves at identical memory behavior.
//  lconv: preload full 14-tap packed window (v[14] u32x4, 14 outstanding
//    loads/thread), 8 t's per thread, unpack-on-use. Read traffic 470->117MB.
constexpr int T_DIM = 4096;
constexpr int B_DIM = 16;
constexpr int C_DIM = 512;
constexpr int K_CONV = 7;
constexpr int M_DIM = T_DIM * B_DIM;   // 65536 GEMM rows
constexpr int BC = B_DIM * C_DIM;      // 8192

typedef __attribute__((ext_vector_type(8))) short bf16x8;
typedef __attribute__((ext_vector_type(4))) float f32x4;
typedef __attribute__((ext_vector_type(8))) float f32x8;
typedef __attribute__((ext_vector_type(4))) unsigned int u32x4;

__device__ __forceinline__ unsigned short f2bf(float f) {
  unsigned u = __float_as_uint(f);
  u += 0x7fffu + ((u >> 16) & 1u);   // RNE
  return (unsigned short)(u >> 16);
}
__device__ __forceinline__ unsigned pack2(float a, float b) {
  return (unsigned)f2bf(a) | (((unsigned)f2bf(b)) << 16);
}

// ---------------------------------------------------------------- quantize W -> bf16
__global__ __launch_bounds__(256) void quantize_w(
    const float* __restrict__ W, unsigned short* __restrict__ Wq) {
  int i = blockIdx.x * 256 + threadIdx.x;
  float w = W[i];
  float a = fabsf(w) + 1e-12f;
  float q = exp2f(rintf(log2f(a)));       // rintf = RNE, matches jnp.round
  q = (w > 0.f) ? q : ((w < 0.f) ? -q : 0.f);
  Wq[i] = f2bf(q);                        // powers of two: exact in bf16
}

// ---------------------------------------------------------------- GEMM (B^T)
// Y[m,n] = sum_k X[m,k]*Bt[n,k] + bias[n]; X fp32 cast in-flight, Bt bf16.
constexpr int BK = 32;
constexpr int NSTEP = C_DIM / BK;   // 16 K-steps

__global__ __launch_bounds__(512, 6) void gemm_bt(
    const float* __restrict__ X, const short* __restrict__ Bt,
    const float* __restrict__ bias, unsigned short* __restrict__ Y) {
  constexpr int K = C_DIM, N = C_DIM;
  // 128 rows x 32 k bf16 = 64 B/row, 8 KB/tile; dbuf A+B = 32 KB.
  __shared__ __align__(16) short As[2][128 * BK];
  __shared__ __align__(16) short Bs[2][128 * BK];

  // XCD swizzle: the 4 n-blocks sharing an X m-tile run consecutively on one XCD.
  const int id   = blockIdx.x;            // 0..2047
  const int xcd  = id & 7;
  const int slot = id >> 3;               // 0..255
  const int nb   = slot & 3;
  const int mb   = xcd * 64 + (slot >> 2);
  const int m0 = mb * 128;
  const int n0 = nb * 128;

  const int t    = threadIdx.x;           // 0..511
  const int lane = t & 63;
  const int wid  = t >> 6;                // 8 waves: 2x4 of 64x32

  // ---- A staging: thread t stages row t>>2 (0..127), float col (t&3)*8.
  const int ar = t >> 2;
  const float* pA = X + (long)(m0 + ar) * K + (t & 3) * 8;
  // swizzled 16B-chunk within 64B row: chunk ^= (row>>1)&3
  const int awoff = (((t & 3) ^ ((ar >> 1) & 3)) << 4);

  // ---- B staging via global_load_lds: linear LDS dest (wave base + lane*16),
  // source pre-swizzled. phys row = wid*16 + (lane>>2), phys chunk = lane&3;
  // logical chunk = phys ^ ((row>>1)&3) = (lane&3) ^ ((lane>>3)&3).
  const int bc = ((lane & 3) ^ ((lane >> 3) & 3)) * 8;   // shorts
  const short* pB = Bt + (long)(n0 + wid * 16 + (lane >> 2)) * K + bc;

  // ---- fragment geometry (A frag: A[m=lane&15][k=(lane>>4)*8+j])
  const int fr = lane & 15;
  const int fq = lane >> 4;
  const int wm = (wid >> 2) * 64;          // 0,64
  const int wn = (wid & 3) * 32;           // 0,32,64,96
  // frag row = wm|wn + i*16 + fr -> (row>>1)&3 = (fr>>1)&3 (wave-constant)
  const int sw = ((fq ^ ((fr >> 1) & 3)) << 4);

  f32x4 ax[2];
  f32x4 acc[4][2] = {};

  auto loadA = [&](int k0) {
    ax[0] = *(const f32x4*)(pA + k0);
    ax[1] = *(const f32x4*)(pA + k0 + 4);
  };
  auto stageB = [&](int bsel, int k0) {
    __builtin_amdgcn_global_load_lds(
        (const __attribute__((address_space(1))) void*)(pB + k0),
        (__attribute__((address_space(3))) void*)&Bs[bsel][wid * 512],
        16, 0, 0);
  };
  auto writeA = [&](int bsel) {
    char* base = (char*)&As[bsel][0];
    u32x4 p;
    p[0] = pack2(ax[0][0], ax[0][1]);
    p[1] = pack2(ax[0][2], ax[0][3]);
    p[2] = pack2(ax[1][0], ax[1][1]);
    p[3] = pack2(ax[1][2], ax[1][3]);
    *(u32x4*)(base + ar * 64 + awoff) = p;
  };
  auto compute = [&](int bsel) {
    const char* ab = (const char*)&As[bsel][0];
    const char* bb = (const char*)&Bs[bsel][0];
    bf16x8 af[4], bfr[2];
#pragma unroll
    for (int i = 0; i < 4; ++i)
      af[i] = *(const bf16x8*)(ab + (wm + i * 16 + fr) * 64 + sw);
#pragma unroll
    for (int j = 0; j < 2; ++j)
      bfr[j] = *(const bf16x8*)(bb + (wn + j * 16 + fr) * 64 + sw);
#pragma unroll
    for (int i = 0; i < 4; ++i)
#pragma unroll
      for (int j = 0; j < 2; ++j)
        acc[i][j] = __builtin_amdgcn_mfma_f32_16x16x32_bf16(af[i], bfr[j], acc[i][j], 0, 0, 0);
  };

  // prologue: stage tile 0
  loadA(0);
  stageB(0, 0);
  writeA(0);
  __syncthreads();

  // main loop: ONE barrier per step; s+1 loads in flight across compute(s)
#pragma unroll
  for (int s = 0; s < NSTEP; ++s) {
    const int buf = s & 1;
    if (s + 1 < NSTEP) {
      loadA((s + 1) * BK);
      stageB(buf ^ 1, (s + 1) * BK);
    }
    compute(buf);
    if (s + 1 < NSTEP) {
      writeA(buf ^ 1);
      __syncthreads();
    }
  }

  // epilogue: C/D layout col=lane&15, row=(lane>>4)*4+reg
#pragma unroll
  for (int j = 0; j < 2; ++j) {
    const int gn = n0 + wn + j * 16 + fr;
    const float bv = bias[gn];
#pragma unroll
    for (int i = 0; i < 4; ++i) {
#pragma unroll
      for (int r = 0; r < 4; ++r) {
        const int gm = m0 + wm + i * 16 + fq * 4 + r;
        Y[(long)gm * N + gn] = f2bf(acc[i][j][r] + bv);
      }
    }
  }
}

// ---------------------------------------------------------------- depthwise conv
// out[t,b,c] = sum_k y[t+k-3,b,c] * softmax(weight[h])[k], h = c>>6.
// 8 t's per thread, full 14-tap packed window preloaded (14 outstanding loads).
constexpr int CHT = 8;

__device__ __forceinline__ u32x4 loadY(const unsigned short* Y, int t, long off) {
  if ((unsigned)t < (unsigned)T_DIM)
    return *(const u32x4*)(Y + (long)t * BC + off);
  u32x4 z = {0u, 0u, 0u, 0u};
  return z;
}

__device__ __forceinline__ f32x8 unpack8(u32x4 u) {
  f32x8 r;
#pragma unroll
  for (int i = 0; i < 4; ++i) {
    unsigned w = u[i];
    r[2 * i]     = __uint_as_float(w << 16);
    r[2 * i + 1] = __uint_as_float(w & 0xffff0000u);
  }
  return r;
}

__global__ __launch_bounds__(256, 6) void lconv(
    const unsigned short* __restrict__ Y, const float* __restrict__ W,
    float* __restrict__ O) {
  __shared__ float sm_wf[8 * K_CONV];
  if (threadIdx.x < 8) {
    const int h = threadIdx.x;
    float v[K_CONV];
    float mx = -1e30f;
#pragma unroll
    for (int k = 0; k < K_CONV; ++k) { v[k] = W[h * K_CONV + k]; mx = fmaxf(mx, v[k]); }
    float s = 0.f;
#pragma unroll
    for (int k = 0; k < K_CONV; ++k) { v[k] = __expf(v[k] - mx); s += v[k]; }
    const float inv = 1.f / s;
#pragma unroll
    for (int k = 0; k < K_CONV; ++k) sm_wf[h * K_CONV + k] = v[k] * inv;
  }

  // XCD swizzle: xcd owns t in [xcd*512, xcd*512+512) for each b.
  const int id   = blockIdx.x;            // 0..2047
  const int xcd  = id & 7;
  const int slot = id >> 3;               // 0..255
  const int b    = slot >> 4;             // 0..15
  const int tl   = slot & 15;             // 0..15
  const int t0   = xcd * 512 + tl * 32 + (threadIdx.x >> 6) * CHT;
  const int cvec = threadIdx.x & 63;
  const long off = (long)b * C_DIM + cvec * 8;
  const int h    = cvec >> 3;

  u32x4 v[CHT + 6];
#pragma unroll
  for (int k = 0; k < CHT + 6; ++k) v[k] = loadY(Y, t0 - 3 + k, off);

  __syncthreads();
  float wf[K_CONV];
#pragma unroll
  for (int k = 0; k < K_CONV; ++k) wf[k] = sm_wf[h * K_CONV + k];

#pragma unroll
  for (int j = 0; j < CHT; ++j) {
    f32x8 acc = unpack8(v[j]) * wf[0];
#pragma unroll
    for (int k = 1; k < K_CONV; ++k) acc += unpack8(v[j + k]) * wf[k];
    float* op = O + (long)(t0 + j) * BC + off;
    *(f32x4*)op       = f32x4{acc[0], acc[1], acc[2], acc[3]};
    *(f32x4*)(op + 4) = f32x4{acc[4], acc[5], acc[6], acc[7]};
  }
}

// ---------------------------------------------------------------- launch
extern "C" void kernel_launch(void* const* d_in, const int* in_sizes, int n_in,
                              void* d_out, int out_size, void* d_ws, size_t ws_size,
                              hipStream_t stream) {
  const float* x       = (const float*)d_in[0];  // (T,B,C) fp32
  const float* shift_W = (const float*)d_in[1];  // (C,C) fp32
  const float* shift_b = (const float*)d_in[2];  // (C) fp32
  const float* weight  = (const float*)d_in[3];  // (8,7) fp32
  float* out = (float*)d_out;

  unsigned short* Wq = (unsigned short*)d_ws;        // 512 KB bf16 Wq
  unsigned short* Y  = Wq + C_DIM * C_DIM;           // 67 MB bf16 y

  quantize_w<<<(C_DIM * C_DIM) / 256, 256, 0, stream>>>(shift_W, Wq);
  gemm_bt<<<(M_DIM / 128) * (C_DIM / 128), 512, 0, stream>>>(
      x, (const short*)Wq, shift_b, Y);
  lconv<<<M_DIM / CHT * (C_DIM / 8) / 256, 256, 0, stream>>>(Y, weight, out);
}

// Round 4
// 301.825 us; speedup vs baseline: 1.1245x; 1.1245x over previous
//
#include <hip/hip_runtime.h>

// LightshiftaddLayer — R9:
//  gemm_bt: R7 base (256 thr, 4 waves 64x64, BK=32, T2 swizzle, gload_lds B)
//    + depth-2 pipeline: THREE LDS buffers, counted s_waitcnt vmcnt(6), raw
//    s_barrier (no drain-to-0). Stage(s+2) stays in flight across the barrier;
//    each stage gets a full iteration of latency cover (was ~0 with dbuf +
//    __syncthreads). 48 KB LDS -> 3 blocks/CU. R8 (more waves, less work/wave)
//    proved occupancy is no longer binding; exposed load latency is.
//  lconv: exact revert to R7 one-t-per-thread (R8's CHT=8 window regressed).
constexpr int T_DIM = 4096;
constexpr int B_DIM = 16;
constexpr int C_DIM = 512;
constexpr int K_CONV = 7;
constexpr int M_DIM = T_DIM * B_DIM;   // 65536 GEMM rows
constexpr int BC = B_DIM * C_DIM;      // 8192

typedef __attribute__((ext_vector_type(8))) short bf16x8;
typedef __attribute__((ext_vector_type(4))) float f32x4;
typedef __attribute__((ext_vector_type(8))) float f32x8;
typedef __attribute__((ext_vector_type(4))) unsigned int u32x4;

__device__ __forceinline__ unsigned short f2bf(float f) {
  unsigned u = __float_as_uint(f);
  u += 0x7fffu + ((u >> 16) & 1u);   // RNE
  return (unsigned short)(u >> 16);
}
__device__ __forceinline__ unsigned pack2(float a, float b) {
  return (unsigned)f2bf(a) | (((unsigned)f2bf(b)) << 16);
}

// ---------------------------------------------------------------- quantize W -> bf16
__global__ __launch_bounds__(256) void quantize_w(
    const float* __restrict__ W, unsigned short* __restrict__ Wq) {
  int i = blockIdx.x * 256 + threadIdx.x;
  float w = W[i];
  float a = fabsf(w) + 1e-12f;
  float q = exp2f(rintf(log2f(a)));       // rintf = RNE, matches jnp.round
  q = (w > 0.f) ? q : ((w < 0.f) ? -q : 0.f);
  Wq[i] = f2bf(q);                        // powers of two: exact in bf16
}

// ---------------------------------------------------------------- GEMM (B^T)
// Y[m,n] = sum_k X[m,k]*Bt[n,k] + bias[n]; X fp32 cast in-flight, Bt bf16.
constexpr int BK = 32;
constexpr int NSTEP = C_DIM / BK;   // 16 K-steps
constexpr int NBUF = 3;             // depth-2 prefetch

__global__ __launch_bounds__(256, 3) void gemm_bt(
    const float* __restrict__ X, const short* __restrict__ Bt,
    const float* __restrict__ bias, unsigned short* __restrict__ Y) {
  constexpr int K = C_DIM, N = C_DIM;
  // 128 rows x 32 k bf16 = 64 B/row, 8 KB/tile; 3 bufs A+B = 48 KB.
  __shared__ __align__(16) short As[NBUF][128 * BK];
  __shared__ __align__(16) short Bs[NBUF][128 * BK];

  // XCD swizzle: the 4 n-blocks sharing an X m-tile run consecutively on one XCD.
  const int id   = blockIdx.x;            // 0..2047
  const int xcd  = id & 7;
  const int slot = id >> 3;               // 0..255
  const int nb   = slot & 3;
  const int mb   = xcd * 64 + (slot >> 2);
  const int m0 = mb * 128;
  const int n0 = nb * 128;

  const int t    = threadIdx.x;
  const int lane = t & 63;
  const int wid  = t >> 6;               // 4 waves: 2x2 of 64x64

  // ---- A staging: thread t stages rows t>>2 and 64+(t>>2), float col (t&3)*8.
  const int ar = t >> 2;                 // 0..63
  const float* pA = X + (long)(m0 + ar) * K + (t & 3) * 8;
  // swizzled 16B-chunk within 64B row: chunk ^= (row>>1)&3 (same for row+64)
  const int awoff = (((t & 3) ^ ((ar >> 1) & 3)) << 4);

  // ---- B staging via global_load_lds: linear LDS dest (wave base + lane*16),
  // source pre-swizzled: logical chunk = (t&3) ^ ((t>>3)&3).
  const int bc = ((t & 3) ^ ((t >> 3) & 3)) * 8;   // shorts
  const short* pB = Bt + (long)(n0 + (t >> 2)) * K + bc;

  // ---- fragment geometry (A frag: A[m=lane&15][k=(lane>>4)*8+j])
  const int fr = lane & 15;
  const int fq = lane >> 4;
  const int wm = (wid >> 1) * 64;
  const int wn = (wid & 1) * 64;
  // frag row = wm|wn + i*16 + fr -> (row>>1)&3 = (fr>>1)&3 (wave-constant)
  const int sw = ((fq ^ ((fr >> 1) & 3)) << 4);

  // bias preloaded BEFORE any stage so the vmcnt ledger only ever has stage
  // ops newer than it (older foreign ops only make counted waits stricter).
  float bv[4];
#pragma unroll
  for (int j = 0; j < 4; ++j) bv[j] = bias[n0 + wn + j * 16 + fr];
  __builtin_amdgcn_sched_barrier(0);

  f32x4 ax[2][4];              // two stage reg-sets, parity = stage & 1
  f32x4 acc[4][4] = {};

  auto loadA = [&](int k0, int p) {
    ax[p][0] = *(const f32x4*)(pA + k0);
    ax[p][1] = *(const f32x4*)(pA + k0 + 4);
    ax[p][2] = *(const f32x4*)(pA + (long)64 * K + k0);
    ax[p][3] = *(const f32x4*)(pA + (long)64 * K + k0 + 4);
  };
  auto stageB = [&](int bsel, int k0) {
#pragma unroll
    for (int i = 0; i < 2; ++i)
      __builtin_amdgcn_global_load_lds(
          (const __attribute__((address_space(1))) void*)(pB + (long)i * 64 * K + k0),
          (__attribute__((address_space(3))) void*)&Bs[bsel][i * 2048 + wid * 512],
          16, 0, 0);
  };
  auto writeA = [&](int bsel, int p) {
    char* base = (char*)&As[bsel][0];
    u32x4 w0, w1;
    w0[0] = pack2(ax[p][0][0], ax[p][0][1]);
    w0[1] = pack2(ax[p][0][2], ax[p][0][3]);
    w0[2] = pack2(ax[p][1][0], ax[p][1][1]);
    w0[3] = pack2(ax[p][1][2], ax[p][1][3]);
    w1[0] = pack2(ax[p][2][0], ax[p][2][1]);
    w1[1] = pack2(ax[p][2][2], ax[p][2][3]);
    w1[2] = pack2(ax[p][3][0], ax[p][3][1]);
    w1[3] = pack2(ax[p][3][2], ax[p][3][3]);
    *(u32x4*)(base + ar * 64 + awoff)        = w0;
    *(u32x4*)(base + (64 + ar) * 64 + awoff) = w1;
  };
  auto compute = [&](int bsel) {
    const char* ab = (const char*)&As[bsel][0];
    const char* bb = (const char*)&Bs[bsel][0];
    bf16x8 af[4], bfr[4];
#pragma unroll
    for (int i = 0; i < 4; ++i)
      af[i] = *(const bf16x8*)(ab + (wm + i * 16 + fr) * 64 + sw);
#pragma unroll
    for (int j = 0; j < 4; ++j)
      bfr[j] = *(const bf16x8*)(bb + (wn + j * 16 + fr) * 64 + sw);
#pragma unroll
    for (int i = 0; i < 4; ++i)
#pragma unroll
      for (int j = 0; j < 4; ++j)
        acc[i][j] = __builtin_amdgcn_mfma_f32_16x16x32_bf16(af[i], bfr[j], acc[i][j], 0, 0, 0);
  };

  // ---- prologue: stages 0 and 1 in flight; wait stage 0 only (vmcnt(6)).
  loadA(0, 0);
  stageB(0, 0);
  __builtin_amdgcn_sched_barrier(0);
  loadA(BK, 1);
  stageB(1, BK);
  __builtin_amdgcn_sched_barrier(0);
  asm volatile("s_waitcnt vmcnt(6)" ::: "memory");   // stage0 A+B complete
  writeA(0, 0);
  asm volatile("s_waitcnt lgkmcnt(0)" ::: "memory");
  __builtin_amdgcn_s_barrier();
  __builtin_amdgcn_sched_barrier(0);

  // ---- main loop: stage(s+2) crosses the barrier; wait stage(s+1) only.
#pragma unroll
  for (int s = 0; s < NSTEP; ++s) {
    if (s + 2 < NSTEP) {
      loadA((s + 2) * BK, s & 1);        // parity (s+2)&1 == s&1
      stageB((s + 2) % NBUF, (s + 2) * BK);
      __builtin_amdgcn_sched_barrier(0);
    }
    compute(s % NBUF);
    if (s + 1 < NSTEP) {
      if (s + 2 < NSTEP)
        asm volatile("s_waitcnt vmcnt(6)" ::: "memory");  // stage(s+1) done
      else
        asm volatile("s_waitcnt vmcnt(0)" ::: "memory");  // tail: all done
      writeA((s + 1) % NBUF, (s + 1) & 1);
      asm volatile("s_waitcnt lgkmcnt(0)" ::: "memory");
      __builtin_amdgcn_s_barrier();
      __builtin_amdgcn_sched_barrier(0);
    }
  }

  // epilogue: C/D layout col=lane&15, row=(lane>>4)*4+reg
#pragma unroll
  for (int j = 0; j < 4; ++j) {
    const int gn = n0 + wn + j * 16 + fr;
#pragma unroll
    for (int i = 0; i < 4; ++i) {
#pragma unroll
      for (int r = 0; r < 4; ++r) {
        const int gm = m0 + wm + i * 16 + fq * 4 + r;
        Y[(long)gm * N + gn] = f2bf(acc[i][j][r] + bv[j]);
      }
    }
  }
}

// ---------------------------------------------------------------- depthwise conv
// out[t,b,c] = sum_k y[t+k-3,b,c] * softmax(weight[h])[k], h = c>>6.
// One t per thread: 7 independent 16B loads, no window state (R7 version).
__device__ __forceinline__ u32x4 loadY(const unsigned short* Y, int t, long off) {
  if ((unsigned)t < (unsigned)T_DIM)
    return *(const u32x4*)(Y + (long)t * BC + off);
  u32x4 z = {0u, 0u, 0u, 0u};
  return z;
}

__device__ __forceinline__ f32x8 unpack8(u32x4 u) {
  f32x8 r;
#pragma unroll
  for (int i = 0; i < 4; ++i) {
    unsigned w = u[i];
    r[2 * i]     = __uint_as_float(w << 16);
    r[2 * i + 1] = __uint_as_float(w & 0xffff0000u);
  }
  return r;
}

__global__ __launch_bounds__(256, 4) void lconv(
    const unsigned short* __restrict__ Y, const float* __restrict__ W,
    float* __restrict__ O) {
  __shared__ float sm_wf[8 * K_CONV];
  if (threadIdx.x < 8) {
    const int h = threadIdx.x;
    float v[K_CONV];
    float mx = -1e30f;
#pragma unroll
    for (int k = 0; k < K_CONV; ++k) { v[k] = W[h * K_CONV + k]; mx = fmaxf(mx, v[k]); }
    float s = 0.f;
#pragma unroll
    for (int k = 0; k < K_CONV; ++k) { v[k] = __expf(v[k] - mx); s += v[k]; }
    const float inv = 1.f / s;
#pragma unroll
    for (int k = 0; k < K_CONV; ++k) sm_wf[h * K_CONV + k] = v[k] * inv;
  }

  // XCD swizzle: xcd owns t in [xcd*512, xcd*512+512) for each b.
  const int id   = blockIdx.x;            // 0..16383
  const int xcd  = id & 7;
  const int slot = id >> 3;               // 0..2047
  const int b    = slot >> 7;             // 0..15
  const int tl   = slot & 127;            // 0..127
  const int t    = xcd * 512 + tl * 4 + (threadIdx.x >> 6);
  const int cvec = threadIdx.x & 63;
  const long off = (long)b * C_DIM + cvec * 8;
  const int h    = cvec >> 3;

  u32x4 v[K_CONV];
#pragma unroll
  for (int k = 0; k < K_CONV; ++k) v[k] = loadY(Y, t + k - 3, off);

  __syncthreads();
  float wf[K_CONV];
#pragma unroll
  for (int k = 0; k < K_CONV; ++k) wf[k] = sm_wf[h * K_CONV + k];

  f32x8 acc = unpack8(v[0]) * wf[0];
#pragma unroll
  for (int k = 1; k < K_CONV; ++k) acc += unpack8(v[k]) * wf[k];

  float* op = O + (long)t * BC + off;
  *(f32x4*)op       = f32x4{acc[0], acc[1], acc[2], acc[3]};
  *(f32x4*)(op + 4) = f32x4{acc[4], acc[5], acc[6], acc[7]};
}

// ---------------------------------------------------------------- launch
extern "C" void kernel_launch(void* const* d_in, const int* in_sizes, int n_in,
                              void* d_out, int out_size, void* d_ws, size_t ws_size,
                              hipStream_t stream) {
  const float* x       = (const float*)d_in[0];  // (T,B,C) fp32
  const float* shift_W = (const float*)d_in[1];  // (C,C) fp32
  const float* shift_b = (const float*)d_in[2];  // (C) fp32
  const float* weight  = (const float*)d_in[3];  // (8,7) fp32
  float* out = (float*)d_out;

  unsigned short* Wq = (unsigned short*)d_ws;        // 512 KB bf16 Wq
  unsigned short* Y  = Wq + C_DIM * C_DIM;           // 67 MB bf16 y

  quantize_w<<<(C_DIM * C_DIM) / 256, 256, 0, stream>>>(shift_W, Wq);
  gemm_bt<<<(M_DIM / 128) * (C_DIM / 128), 256, 0, stream>>>(
      x, (const short*)Wq, shift_b, Y);
  lconv<<<M_DIM * (C_DIM / 8) / 256, 256, 0, stream>>>(Y, weight, out);
}